// Round 1
// baseline (8523.875 us; speedup 1.0000x reference)
//
#include <hip/hip_runtime.h>

// LSTM T=512, B=64, E=512, H=1024. Persistent fused kernel:
//  - 256 blocks x 256 threads (1/CU). Block (bg, cg): batch group bg (32 rows),
//    col group cg: 8 h-features x 4 gates = 32 gate-columns.
//  - Weights bf16, register-resident B-fragments (24 x bf16x8 per lane).
//  - K=1536 split across 4 waves, MFMA 32x32x16, LDS reduce.
//  - Per-step device barrier (counter in ws), double-buffered bf16 h.
//  - h published via agent-scope atomic u32 stores (LLC), acquire fence on read.

typedef __bf16 bf16x8 __attribute__((ext_vector_type(8)));
typedef float f32x16 __attribute__((ext_vector_type(16)));

#define T_STEPS 512
#define OUT_HALF ((size_t)512 * 64 * 1024)

// ws layout (bytes)
#define WB_OFF  0u            // bf16 [4096][1536], row r = feat*4 + gate
#define XB_OFF  12582912u     // bf16 [512][64][512]
#define HB_OFF  46137344u     // bf16 [2][64][1024]
#define CTR_OFF 46399488u     // u32 barrier counter
#define WS_NEED (46399488u + 128u)

__device__ __forceinline__ unsigned short f2b(float x) {
  unsigned u = __builtin_bit_cast(unsigned, x);
  return (unsigned short)((u + 0x7fffu + ((u >> 16) & 1u)) >> 16);
}
__device__ __forceinline__ float sigmoid_f(float x) {
  x = fminf(fmaxf(x, -30.f), 30.f);
  return 1.f / (1.f + __expf(-x));
}
__device__ __forceinline__ float tanh_f(float x) {
  x = fminf(fmaxf(x, -15.f), 15.f);
  float e = __expf(2.f * x);
  return (e - 1.f) / (e + 1.f);
}

__global__ void prep_kernel(const float* __restrict__ embeds,
                            const float* __restrict__ Wg, const float* __restrict__ Wi,
                            const float* __restrict__ Wf, const float* __restrict__ Wo,
                            unsigned short* __restrict__ Xb, unsigned short* __restrict__ Wb,
                            unsigned short* __restrict__ hb, unsigned* __restrict__ ctr) {
  const size_t tid = (size_t)blockIdx.x * blockDim.x + threadIdx.x;
  const size_t nth = (size_t)gridDim.x * blockDim.x;
  // embeds -> bf16 (16,777,216 elems, 4 at a time)
  for (size_t i = tid; i < 16777216u / 4; i += nth) {
    const float4 v = ((const float4*)embeds)[i];
    ushort4 o;
    o.x = f2b(v.x); o.y = f2b(v.y); o.z = f2b(v.z); o.w = f2b(v.w);
    ((ushort4*)Xb)[i] = o;
  }
  // weights -> bf16, interleaved rows r = feat*4 + gate (gate: 0=g,1=i,2=f,3=o)
  const float* Ws[4] = {Wg, Wi, Wf, Wo};
  for (size_t i = tid; i < 6291456u / 4; i += nth) {
    const size_t r = i / 384;      // 1536/4 float4 per row
    const size_t kq = i % 384;
    const int gate = (int)(r & 3);
    const size_t feat = r >> 2;
    const float4 v = ((const float4*)(Ws[gate] + feat * 1536))[kq];
    ushort4 o;
    o.x = f2b(v.x); o.y = f2b(v.y); o.z = f2b(v.z); o.w = f2b(v.w);
    ((ushort4*)Wb)[i] = o;
  }
  // zero both h buffers (2*64*1024 bf16 = 65536 u32)
  for (size_t i = tid; i < 65536u; i += nth) ((unsigned*)hb)[i] = 0u;
  if (tid == 0) *ctr = 0u;
}

__launch_bounds__(256, 1)
__global__ void lstm_persist(const unsigned short* __restrict__ Wb,
                             const unsigned short* __restrict__ Xb,
                             unsigned short* __restrict__ hb,
                             unsigned* __restrict__ ctr,
                             const float* __restrict__ bgv, const float* __restrict__ biv,
                             const float* __restrict__ bfv, const float* __restrict__ bov,
                             float* __restrict__ out) {
  const int tid = threadIdx.x;
  const int lane = tid & 63;
  const int wave = tid >> 6;        // 0..3 (K-split)
  const int blk = blockIdx.x;       // 0..255
  const int bgp = blk & 1;          // batch group: batches bgp*32..+32
  const int cg = blk >> 1;          // col group: feats cg*8..+8 (x4 gates)

  __shared__ float red[4][32][33];  // K-split partial accs
  __shared__ float hst[32][9];
  __shared__ float cst[32][9];

  // ---- load register-resident B fragments (weights, bf16) ----
  // B frag for 32x32x16: lane holds B[k=(lane>>5)*8 + j][col=lane&31].
  // Wb stored as [col_row][k] so 8 contiguous k per lane = one 16B load.
  bf16x8 Bf[24];
  {
    const int c = lane & 31;
    const int khw = (lane >> 5) * 8;
    const unsigned short* wrow = Wb + (size_t)(cg * 32 + c) * 1536 + khw;
#pragma unroll
    for (int i = 0; i < 24; ++i) {
      const int j = wave + 4 * i;   // K-iter index 0..95, strided across waves
      Bf[i] = *(const bf16x8*)(const void*)(wrow + j * 16);
    }
  }

  // epilogue thread mapping: (bat, fi)
  const int ep_bat = tid & 31;
  const int ep_fi = tid >> 5;       // 0..7
  const int feat = cg * 8 + ep_fi;
  const float bias_g = bgv[feat], bias_i = biv[feat], bias_f = bfv[feat], bias_o = bov[feat];

  const int arow = bgp * 32 + (lane & 31);  // batch row for A fragments
  const int kh = (lane >> 5) * 8;
  const int st_bat = tid >> 3, st_f = tid & 7;  // coalesced-store mapping
  float c_reg = 0.f;

  float* outH = out;
  float* outC = out + OUT_HALF;

#pragma unroll 1
  for (int t = 0; t < T_STEPS; ++t) {
    f32x16 acc0 = {};
    f32x16 acc1 = {};

    // ---- x-part GEMM (K 0..512) — independent of barrier, hides sync latency
    const unsigned short* xrow = Xb + ((size_t)t * 64 + arow) * 512 + kh;
#pragma unroll
    for (int i = 0; i < 8; i += 2) {
      const int j0 = wave + 4 * i;
      const int j1 = wave + 4 * (i + 1);
      bf16x8 a0 = *(const bf16x8*)(const void*)(xrow + j0 * 16);
      bf16x8 a1 = *(const bf16x8*)(const void*)(xrow + j1 * 16);
      acc0 = __builtin_amdgcn_mfma_f32_32x32x16_bf16(a0, Bf[i], acc0, 0, 0, 0);
      acc1 = __builtin_amdgcn_mfma_f32_32x32x16_bf16(a1, Bf[i + 1], acc1, 0, 0, 0);
    }

    // ---- wait for h_{t-1} (all blocks arrived t times) ----
    if (tid == 0) {
      const unsigned target = (unsigned)t * 256u;
      while (__hip_atomic_load(ctr, __ATOMIC_RELAXED, __HIP_MEMORY_SCOPE_AGENT) < target) {
      }
    }
    __syncthreads();
    __builtin_amdgcn_fence(__ATOMIC_ACQUIRE, "agent");  // invalidate stale L1/L2

    // ---- h-part GEMM (K 512..1536) from bf16 h buffer (double-buffered) ----
    const unsigned short* hrow = hb + (size_t)(t & 1) * 65536 + (size_t)arow * 1024 + kh;
#pragma unroll
    for (int i = 8; i < 24; i += 2) {
      const int j0 = wave + 4 * i;
      const int j1 = wave + 4 * (i + 1);
      bf16x8 a0 = *(const bf16x8*)(const void*)(hrow + (j0 - 32) * 16);
      bf16x8 a1 = *(const bf16x8*)(const void*)(hrow + (j1 - 32) * 16);
      acc0 = __builtin_amdgcn_mfma_f32_32x32x16_bf16(a0, Bf[i], acc0, 0, 0, 0);
      acc1 = __builtin_amdgcn_mfma_f32_32x32x16_bf16(a1, Bf[i + 1], acc1, 0, 0, 0);
    }

    // ---- K-split reduce via LDS ----
    // C/D layout 32x32: col=lane&31, row=(r&3)+8*(r>>2)+4*(lane>>5)
#pragma unroll
    for (int r = 0; r < 16; ++r) {
      const int row = (r & 3) + 8 * (r >> 2) + 4 * (lane >> 5);
      red[wave][row][lane & 31] = acc0[r] + acc1[r];
    }
    __syncthreads();

    // ---- epilogue: one (batch, feature) per thread ----
    float pg = bias_g, pi = bias_i, pf = bias_f, po = bias_o;
#pragma unroll
    for (int w = 0; w < 4; ++w) {
      pg += red[w][ep_bat][ep_fi * 4 + 0];
      pi += red[w][ep_bat][ep_fi * 4 + 1];
      pf += red[w][ep_bat][ep_fi * 4 + 2];
      po += red[w][ep_bat][ep_fi * 4 + 3];
    }
    const float gt = tanh_f(pg);
    const float it = sigmoid_f(pi);
    const float ft = sigmoid_f(pf);
    const float ot = sigmoid_f(po);
    const float cn = ft * c_reg + it * gt;
    const float hn = ot * tanh_f(cn);
    c_reg = cn;
    hst[ep_bat][ep_fi] = hn;
    cst[ep_bat][ep_fi] = cn;
    __syncthreads();

    // ---- outputs (fp32, nontemporal) ----
    const size_t obase = ((size_t)t * 64 + bgp * 32 + st_bat) * 1024 + (size_t)cg * 8 + st_f;
    __builtin_nontemporal_store(hst[st_bat][st_f], outH + obase);
    __builtin_nontemporal_store(cst[st_bat][st_f], outC + obase);

    // ---- publish h_t as bf16 into next buffer (agent-scope => LLC) ----
    if (tid < 128) {
      const int batp = tid >> 2, fp = tid & 3;
      const unsigned lo = (unsigned)f2b(hst[batp][2 * fp]);
      const unsigned hi = (unsigned)f2b(hst[batp][2 * fp + 1]);
      unsigned* dst = (unsigned*)(void*)(hb + (size_t)((t + 1) & 1) * 65536)
                      + ((size_t)(bgp * 32 + batp) * 512 + (size_t)cg * 4 + fp);
      __hip_atomic_store(dst, lo | (hi << 16), __ATOMIC_RELAXED, __HIP_MEMORY_SCOPE_AGENT);
    }
    __syncthreads();  // per-wave vmcnt(0) drain: all h stores performed

    // ---- arrive ----
    if (tid == 0) {
      __hip_atomic_fetch_add(ctr, 1u, __ATOMIC_RELEASE, __HIP_MEMORY_SCOPE_AGENT);
    }
  }
}

extern "C" void kernel_launch(void* const* d_in, const int* in_sizes, int n_in,
                              void* d_out, int out_size, void* d_ws, size_t ws_size,
                              hipStream_t stream) {
  if (ws_size < (size_t)WS_NEED) return;  // insufficient scratch: fail visibly

  const float* embeds = (const float*)d_in[0];
  const float* Wg = (const float*)d_in[1];
  const float* Wi = (const float*)d_in[2];
  const float* Wf = (const float*)d_in[3];
  const float* Wo = (const float*)d_in[4];
  const float* bg = (const float*)d_in[5];
  const float* bi = (const float*)d_in[6];
  const float* bf = (const float*)d_in[7];
  const float* bo = (const float*)d_in[8];

  char* ws = (char*)d_ws;
  unsigned short* Wb = (unsigned short*)(ws + WB_OFF);
  unsigned short* Xb = (unsigned short*)(ws + XB_OFF);
  unsigned short* hb = (unsigned short*)(ws + HB_OFF);
  unsigned* ctr = (unsigned*)(ws + CTR_OFF);

  prep_kernel<<<1024, 256, 0, stream>>>(embeds, Wg, Wi, Wf, Wo, Xb, Wb, hb, ctr);
  lstm_persist<<<256, 256, 0, stream>>>(Wb, Xb, hb, ctr, bg, bi, bf, bo, (float*)d_out);
}

// Round 2
// 4820.639 us; speedup vs baseline: 1.7682x; 1.7682x over previous
//
#include <hip/hip_runtime.h>

// LSTM T=512, B=64, E=512, H=1024. Persistent fused kernel, round 2:
//  - 256 blocks x 256 threads (1/CU). Block (bgp, cg): batch group bgp (32 rows),
//    col group cg: 8 h-features x 4 gates = 32 gate-columns.
//  - Weights bf16, register-resident B-fragments (24 x bf16x8 per lane).
//  - K=1536 split across 4 waves, MFMA 32x32x16, LDS reduce.
//  - Sync: distributed flag barrier per batch group (128 flags, relaxed agent
//    stores; wave0 polls via 64x u64 loads). NO acquire fence, NO atomic RMW:
//    h and flags are read with agent-scope relaxed loads (performed at LLC),
//    so L2 stays warm with Xb/Wb across steps.

typedef __bf16 bf16x8 __attribute__((ext_vector_type(8)));
typedef float f32x16 __attribute__((ext_vector_type(16)));

#define T_STEPS 512
#define OUT_HALF ((size_t)512 * 64 * 1024)

// ws layout (bytes)
#define WB_OFF   0u            // bf16 [4096][1536], row r = feat*4 + gate
#define XB_OFF   12582912u     // bf16 [512][64][512]
#define HB_OFF   46137344u     // bf16 [2][64][1024]
#define SLOT_OFF 46399488u     // u32 [2][128] arrival flags
#define WS_NEED  (46399488u + 1024u + 128u)

__device__ __forceinline__ unsigned short f2b(float x) {
  unsigned u = __builtin_bit_cast(unsigned, x);
  return (unsigned short)((u + 0x7fffu + ((u >> 16) & 1u)) >> 16);
}
__device__ __forceinline__ float sigmoid_f(float x) {
  x = fminf(fmaxf(x, -30.f), 30.f);
  return 1.f / (1.f + __expf(-x));
}
__device__ __forceinline__ float tanh_f(float x) {
  x = fminf(fmaxf(x, -15.f), 15.f);
  float e = __expf(2.f * x);
  return (e - 1.f) / (e + 1.f);
}

__global__ void prep_kernel(const float* __restrict__ embeds,
                            const float* __restrict__ Wg, const float* __restrict__ Wi,
                            const float* __restrict__ Wf, const float* __restrict__ Wo,
                            unsigned short* __restrict__ Xb, unsigned short* __restrict__ Wb,
                            unsigned short* __restrict__ hb, unsigned* __restrict__ slots) {
  const size_t tid = (size_t)blockIdx.x * blockDim.x + threadIdx.x;
  const size_t nth = (size_t)gridDim.x * blockDim.x;
  // embeds -> bf16 (16,777,216 elems, 4 at a time)
  for (size_t i = tid; i < 16777216u / 4; i += nth) {
    const float4 v = ((const float4*)embeds)[i];
    ushort4 o;
    o.x = f2b(v.x); o.y = f2b(v.y); o.z = f2b(v.z); o.w = f2b(v.w);
    ((ushort4*)Xb)[i] = o;
  }
  // weights -> bf16, interleaved rows r = feat*4 + gate (gate: 0=g,1=i,2=f,3=o)
  const float* Ws[4] = {Wg, Wi, Wf, Wo};
  for (size_t i = tid; i < 6291456u / 4; i += nth) {
    const size_t r = i / 384;      // 1536/4 float4 per row
    const size_t kq = i % 384;
    const int gate = (int)(r & 3);
    const size_t feat = r >> 2;
    const float4 v = ((const float4*)(Ws[gate] + feat * 1536))[kq];
    ushort4 o;
    o.x = f2b(v.x); o.y = f2b(v.y); o.z = f2b(v.z); o.w = f2b(v.w);
    ((ushort4*)Wb)[i] = o;
  }
  // zero both h buffers at LLC (sc1 stores; nobody ever caches hb in L2)
  for (size_t i = tid; i < 65536u; i += nth)
    __hip_atomic_store(((unsigned*)hb) + i, 0u, __ATOMIC_RELAXED, __HIP_MEMORY_SCOPE_AGENT);
  // zero arrival flags
  for (size_t i = tid; i < 256u; i += nth)
    __hip_atomic_store(slots + i, 0u, __ATOMIC_RELAXED, __HIP_MEMORY_SCOPE_AGENT);
}

__launch_bounds__(256, 1)
__global__ void lstm_persist(const unsigned short* __restrict__ Wb,
                             const unsigned short* __restrict__ Xb,
                             unsigned short* __restrict__ hb,
                             unsigned* __restrict__ slots,
                             const float* __restrict__ bgv, const float* __restrict__ biv,
                             const float* __restrict__ bfv, const float* __restrict__ bov,
                             float* __restrict__ out) {
  const int tid = threadIdx.x;
  const int lane = tid & 63;
  const int wave = tid >> 6;        // 0..3 (K-split)
  const int blk = blockIdx.x;       // 0..255
  const int bgp = blk & 1;          // batch group: batches bgp*32..+32
  const int cg = blk >> 1;          // col group: feats cg*8..+8 (x4 gates)

  __shared__ float red[4][32][33];  // K-split partial accs
  __shared__ float hst[32][9];
  __shared__ float cst[32][9];

  // ---- load register-resident B fragments (weights, bf16) ----
  // B frag for 32x32x16: lane holds B[k=(lane>>5)*8 + j][col=lane&31].
  // Wb stored as [col_row][k] so 8 contiguous k per lane = one 16B load.
  bf16x8 Bf[24];
  {
    const int c = lane & 31;
    const int khw = (lane >> 5) * 8;
    const unsigned short* wrow = Wb + (size_t)(cg * 32 + c) * 1536 + khw;
#pragma unroll
    for (int i = 0; i < 24; ++i) {
      const int j = wave + 4 * i;   // K-iter index 0..95, strided across waves
      Bf[i] = *(const bf16x8*)(const void*)(wrow + j * 16);
    }
  }

  // epilogue thread mapping: (bat, fi)
  const int ep_bat = tid & 31;
  const int ep_fi = tid >> 5;       // 0..7
  const int feat = cg * 8 + ep_fi;
  const float bias_g = bgv[feat], bias_i = biv[feat], bias_f = bfv[feat], bias_o = bov[feat];

  const int arow = bgp * 32 + (lane & 31);  // batch row for A fragments
  const int kh = (lane >> 5) * 8;
  const int st_bat = tid >> 3, st_f = tid & 7;  // coalesced-store mapping
  float c_reg = 0.f;

  float* outH = out;
  float* outC = out + OUT_HALF;
  unsigned* myslots = slots + bgp * 128;

#pragma unroll 1
  for (int t = 0; t < T_STEPS; ++t) {
    f32x16 acc0 = {};
    f32x16 acc1 = {};

    // ---- x-part GEMM (K 0..512) — independent of barrier, hides sync latency
    const unsigned short* xrow = Xb + ((size_t)t * 64 + arow) * 512 + kh;
#pragma unroll
    for (int i = 0; i < 8; i += 2) {
      const int j0 = wave + 4 * i;
      const int j1 = wave + 4 * (i + 1);
      bf16x8 a0 = *(const bf16x8*)(const void*)(xrow + j0 * 16);
      bf16x8 a1 = *(const bf16x8*)(const void*)(xrow + j1 * 16);
      acc0 = __builtin_amdgcn_mfma_f32_32x32x16_bf16(a0, Bf[i], acc0, 0, 0, 0);
      acc1 = __builtin_amdgcn_mfma_f32_32x32x16_bf16(a1, Bf[i + 1], acc1, 0, 0, 0);
    }

    // ---- wait for h_{t-1}: all 128 blocks of this batch group arrived t ----
    if (tid < 64) {
      const unsigned long long* sp = (const unsigned long long*)(myslots) + tid;
      for (;;) {
        const unsigned long long v =
            __hip_atomic_load(sp, __ATOMIC_RELAXED, __HIP_MEMORY_SCOPE_AGENT);
        const bool ok = ((unsigned)v >= (unsigned)t) && ((unsigned)(v >> 32) >= (unsigned)t);
        if (__all(ok)) break;
      }
    }
    __syncthreads();

    // ---- h-part GEMM (K 512..1536); agent-scope loads (LLC), no fence ----
    const unsigned long long* hq =
        (const unsigned long long*)(hb + (size_t)(t & 1) * 65536 + (size_t)arow * 1024 + kh);
#pragma unroll
    for (int i = 8; i < 24; i += 2) {
      const int j0 = wave + 4 * i;
      const int j1 = wave + 4 * (i + 1);
      union { unsigned long long q[2]; bf16x8 v; } ua0, ua1;
      ua0.q[0] = __hip_atomic_load(hq + (j0 - 32) * 4 + 0, __ATOMIC_RELAXED, __HIP_MEMORY_SCOPE_AGENT);
      ua0.q[1] = __hip_atomic_load(hq + (j0 - 32) * 4 + 1, __ATOMIC_RELAXED, __HIP_MEMORY_SCOPE_AGENT);
      ua1.q[0] = __hip_atomic_load(hq + (j1 - 32) * 4 + 0, __ATOMIC_RELAXED, __HIP_MEMORY_SCOPE_AGENT);
      ua1.q[1] = __hip_atomic_load(hq + (j1 - 32) * 4 + 1, __ATOMIC_RELAXED, __HIP_MEMORY_SCOPE_AGENT);
      acc0 = __builtin_amdgcn_mfma_f32_32x32x16_bf16(ua0.v, Bf[i], acc0, 0, 0, 0);
      acc1 = __builtin_amdgcn_mfma_f32_32x32x16_bf16(ua1.v, Bf[i + 1], acc1, 0, 0, 0);
    }

    // ---- K-split reduce via LDS ----
    // C/D layout 32x32: col=lane&31, row=(r&3)+8*(r>>2)+4*(lane>>5)
#pragma unroll
    for (int r = 0; r < 16; ++r) {
      const int row = (r & 3) + 8 * (r >> 2) + 4 * (lane >> 5);
      red[wave][row][lane & 31] = acc0[r] + acc1[r];
    }
    __syncthreads();

    // ---- epilogue: one (batch, feature) per thread ----
    float pg = bias_g, pi = bias_i, pf = bias_f, po = bias_o;
#pragma unroll
    for (int w = 0; w < 4; ++w) {
      pg += red[w][ep_bat][ep_fi * 4 + 0];
      pi += red[w][ep_bat][ep_fi * 4 + 1];
      pf += red[w][ep_bat][ep_fi * 4 + 2];
      po += red[w][ep_bat][ep_fi * 4 + 3];
    }
    const float gt = tanh_f(pg);
    const float it = sigmoid_f(pi);
    const float ft = sigmoid_f(pf);
    const float ot = sigmoid_f(po);
    const float cn = ft * c_reg + it * gt;
    const float hn = ot * tanh_f(cn);
    c_reg = cn;
    hst[ep_bat][ep_fi] = hn;
    cst[ep_bat][ep_fi] = cn;
    __syncthreads();

    // ---- publish h_t as bf16 u64-packs into next buffer (LLC, relaxed) ----
    if (tid < 64) {
      const int batp = tid >> 1, fp = tid & 1;  // 4 feats per thread
      const unsigned lo = (unsigned)f2b(hst[batp][4 * fp + 0]) |
                          ((unsigned)f2b(hst[batp][4 * fp + 1]) << 16);
      const unsigned hi = (unsigned)f2b(hst[batp][4 * fp + 2]) |
                          ((unsigned)f2b(hst[batp][4 * fp + 3]) << 16);
      unsigned long long* dst = (unsigned long long*)(void*)(hb + (size_t)((t + 1) & 1) * 65536)
                                + ((size_t)(bgp * 32 + batp) * 256 + (size_t)cg * 2 + fp);
      __hip_atomic_store(dst, (unsigned long long)lo | ((unsigned long long)hi << 32),
                         __ATOMIC_RELAXED, __HIP_MEMORY_SCOPE_AGENT);
    }
    // drain this wave's stores, then barrier: all publish stores performed at LLC
    asm volatile("s_waitcnt vmcnt(0)" ::: "memory");
    __syncthreads();

    // ---- arrive: distinct address per block, no RMW, no cache flush ----
    if (tid == 0) {
      __hip_atomic_store(myslots + cg, (unsigned)(t + 1),
                         __ATOMIC_RELAXED, __HIP_MEMORY_SCOPE_AGENT);
    }

    // ---- outputs (fp32, nontemporal) — off the critical path ----
    const size_t obase = ((size_t)t * 64 + bgp * 32 + st_bat) * 1024 + (size_t)cg * 8 + st_f;
    __builtin_nontemporal_store(hst[st_bat][st_f], outH + obase);
    __builtin_nontemporal_store(cst[st_bat][st_f], outC + obase);
  }
}

extern "C" void kernel_launch(void* const* d_in, const int* in_sizes, int n_in,
                              void* d_out, int out_size, void* d_ws, size_t ws_size,
                              hipStream_t stream) {
  if (ws_size < (size_t)WS_NEED) return;  // insufficient scratch: fail visibly

  const float* embeds = (const float*)d_in[0];
  const float* Wg = (const float*)d_in[1];
  const float* Wi = (const float*)d_in[2];
  const float* Wf = (const float*)d_in[3];
  const float* Wo = (const float*)d_in[4];
  const float* bg = (const float*)d_in[5];
  const float* bi = (const float*)d_in[6];
  const float* bf = (const float*)d_in[7];
  const float* bo = (const float*)d_in[8];

  char* ws = (char*)d_ws;
  unsigned short* Wb = (unsigned short*)(ws + WB_OFF);
  unsigned short* Xb = (unsigned short*)(ws + XB_OFF);
  unsigned short* hb = (unsigned short*)(ws + HB_OFF);
  unsigned* slots = (unsigned*)(ws + SLOT_OFF);

  prep_kernel<<<1024, 256, 0, stream>>>(embeds, Wg, Wi, Wf, Wo, Xb, Wb, hb, slots);
  lstm_persist<<<256, 256, 0, stream>>>(Wb, Xb, hb, slots, bg, bi, bf, bo, (float*)d_out);
}